// Round 11
// baseline (279.243 us; speedup 1.0000x reference)
//
#include <hip/hip_runtime.h>
#include <hip/hip_bf16.h>
#include <math.h>

#define DIM 128
#define NHEAD 8
#define DHEAD 16
#define HID 512
#define LN_EPS 1e-5f
// (1/sqrt(128))*log2(e) folded into q so softmax runs in exp2 domain
#define QSCALE 0.12751879104863297f

typedef __bf16 bf16x8 __attribute__((ext_vector_type(8)));
typedef float f32x4 __attribute__((ext_vector_type(4)));
typedef float f32x2 __attribute__((ext_vector_type(2)));
typedef _Float16 f16x2 __attribute__((ext_vector_type(2)));

__device__ inline float bf2f(unsigned int bits16) {
    return __uint_as_float(bits16 << 16);
}
__device__ inline unsigned short f2bf(float f) {
    unsigned int u = __float_as_uint(f);
    unsigned int r = u + 0x7fff + ((u >> 16) & 1);   // RNE
    return (unsigned short)(r >> 16);
}
__device__ inline unsigned short f2h(float f) {
    _Float16 h = (_Float16)f;
    return __builtin_bit_cast(unsigned short, h);
}
__device__ inline float h2f(unsigned short h) {
    return (float)__builtin_bit_cast(_Float16, h);
}
// pack two floats -> two OCP e4m3 bytes (low ushort)
__device__ inline unsigned short pk_fp8(float a, float b) {
    int r = __builtin_amdgcn_cvt_pk_fp8_f32(a, b, 0, false);
    return (unsigned short)(r & 0xffff);
}
// unpack 2 fp8 bytes; HI=false: bytes 0,1; HI=true: bytes 2,3
template <bool HI>
__device__ inline f32x2 unpk_fp8(unsigned int w) {
    return __builtin_amdgcn_cvt_pk_f32_fp8((int)w, HI);
}
__device__ inline float fexp2(float x) { return __builtin_amdgcn_exp2f(x); }

// async global->LDS, 16B per lane
__device__ inline void gload_lds16(const void* g, void* l) {
    __builtin_amdgcn_global_load_lds(
        (const __attribute__((address_space(1))) unsigned int*)g,
        (__attribute__((address_space(3))) unsigned int*)l, 16, 0, 0);
}

// ---------------- k1: prep (feat->bf16, weight transposes) + count atomics ----------------
// counts zeroed by hipMemsetAsync before this kernel. No LDS -> full occupancy for atomics.
__global__ __launch_bounds__(256) void prep_count_kernel(
        int* counts, int Nn,
        const float* __restrict__ feat, unsigned short* __restrict__ featb,
        const float* __restrict__ Wq, const float* __restrict__ Wk, const float* __restrict__ Wv,
        unsigned short* __restrict__ Wqkvt,
        const float* __restrict__ W1, unsigned short* __restrict__ W1t,
        const float* __restrict__ W2, unsigned short* __restrict__ W2t,
        const int* __restrict__ dst, int E, int fb, int wb) {
    int blk = blockIdx.x, t = threadIdx.x;
    if (blk < fb) {
        int i = blk * 256 + t;            // quad index
        if (i < Nn * 32) {
            float4 v = *(const float4*)(feat + (size_t)i * 4);
            ushort4 o;
            o.x = f2bf(v.x); o.y = f2bf(v.y); o.z = f2bf(v.z); o.w = f2bf(v.w);
            *(ushort4*)(featb + (size_t)i * 4) = o;
        }
    } else if (blk < wb) {
        int b2_ = blk - fb;
        if (b2_ < 192) {
            int sec = b2_ >> 6;
            const float* W = sec == 0 ? Wq : (sec == 1 ? Wk : Wv);
            int o = (b2_ & 63) * 256 + t;
            int oc = o >> 7, orow = o & 127;
            Wqkvt[sec * 16384 + o] = f2bf(W[(size_t)orow * 128 + oc]);
        } else if (b2_ < 448) {
            int o = (b2_ - 192) * 256 + t;
            int oc = o >> 7, orow = o & 127;
            W1t[o] = f2bf(W1[(size_t)orow * 512 + oc]);
        } else {
            int o = (b2_ - 448) * 256 + t;
            int oc = o >> 9, orow = o & 511;
            W2t[o] = f2bf(W2[(size_t)orow * 128 + oc]);
        }
    } else {
        int e0 = (blk - wb) * 1024 + t * 4;
        if (e0 + 3 < E) {
            int4 d = *(const int4*)(dst + e0);
            atomicAdd(&counts[d.x], 1);
            atomicAdd(&counts[d.y], 1);
            atomicAdd(&counts[d.z], 1);
            atomicAdd(&counts[d.w], 1);
        } else {
            for (int e = e0; e < E; ++e) atomicAdd(&counts[dst[e]], 1);
        }
    }
}

// ---------------- scan ----------------

__global__ __launch_bounds__(256) void scanA_kernel(const int* __restrict__ counts, int* bsum, int Nn) {
    int blk = blockIdx.x, t = threadIdx.x;
    int i = blk * 1024 + t * 4;
    int s = 0;
    if (i < Nn) { int4 x = *(const int4*)(counts + i); s = x.x + x.y + x.z + x.w; }
#pragma unroll
    for (int off = 1; off < 64; off <<= 1) s += __shfl_xor(s, off, 64);
    __shared__ int wt[4];
    if ((t & 63) == 0) wt[t >> 6] = s;
    __syncthreads();
    if (t == 0) bsum[blk] = wt[0] + wt[1] + wt[2] + wt[3];
}

__global__ __launch_bounds__(256) void scanC_kernel(int* counts, const int* __restrict__ bsum,
                                                    int* offsets, int Nn, int NCH) {
    int blk = blockIdx.x, t = threadIdx.x, lane = t & 63, wv = t >> 6;
    __shared__ int wt[4];
    __shared__ int base_s;
    if (wv == 0) {
        int v = (lane < NCH) ? bsum[lane] : 0;
        int s = v;
#pragma unroll
        for (int off = 1; off < 64; off <<= 1) {
            int u = __shfl_up(s, off, 64);
            if (lane >= off) s += u;
        }
        int basev = (blk > 0) ? __shfl(s, blk - 1, 64) : 0;
        int tot = __shfl(s, NCH - 1, 64);
        if (lane == 0) {
            base_s = basev;
            if (blk == 0) offsets[Nn] = tot;
        }
    }
    int i = blk * 1024 + t * 4;
    int4 x = make_int4(0, 0, 0, 0);
    if (i < Nn) x = *(const int4*)(counts + i);
    int ts = x.x + x.y + x.z + x.w;
    int s = ts;
#pragma unroll
    for (int off = 1; off < 64; off <<= 1) {
        int u = __shfl_up(s, off, 64);
        if (lane >= off) s += u;
    }
    if (lane == 63) wt[wv] = s;
    __syncthreads();
    int woff = 0;
    for (int wi = 0; wi < wv; ++wi) woff += wt[wi];
    int excl = base_s + woff + (s - ts);
    if (i < Nn) {
        int o0 = excl, o1 = o0 + x.x, o2 = o1 + x.y, o3 = o2 + x.z;
        *(int4*)(offsets + i) = make_int4(o0, o1, o2, o3);
        *(int4*)(counts + i) = make_int4(o0, o1, o2, o3);
    }
}

// ---------------- k4: fill (CSR scatter) — no LDS, high occupancy ----------------
__global__ void fill_kernel(const int* __restrict__ dst, const int* __restrict__ src,
                            int* cursor, int* srcs, int E) {
    int e0 = (blockIdx.x * blockDim.x + threadIdx.x) * 4;
    if (e0 + 3 < E) {
        int4 d = *(const int4*)(dst + e0);
        int4 sv = *(const int4*)(src + e0);
        srcs[atomicAdd(&cursor[d.x], 1)] = sv.x;
        srcs[atomicAdd(&cursor[d.y], 1)] = sv.y;
        srcs[atomicAdd(&cursor[d.z], 1)] = sv.z;
        srcs[atomicAdd(&cursor[d.w], 1)] = sv.w;
    } else {
        for (int e = e0; e < E; ++e) srcs[atomicAdd(&cursor[dst[e]], 1)] = src[e];
    }
}

// ---------------- k5: qkv GEMM -> f16 q (pre-scaled), fp8 kv8 table ----------------
// grid (3, MP/128): region 0:q 1:k 2:v. kv8 per node: 128B k-fp8 | 128B v-fp8 (dim order).
#define QST 136
__global__ __launch_bounds__(256) void qkv_gemm(
        const unsigned short* __restrict__ A, const unsigned short* __restrict__ Bt,
        unsigned short* __restrict__ qb, unsigned char* __restrict__ kv8) {
    __shared__ unsigned short smem[128 * QST];
    unsigned short* As = smem;
    unsigned short* Bs = smem + 4096;
    int t = threadIdx.x;
    int wave = t >> 6, lane = t & 63;
    int wr = wave >> 1, wc = wave & 1;
    int lrow = lane & 15, kq = lane >> 4;
    int m0 = blockIdx.y * 128;
    int region = blockIdx.x;
    int n0 = region * 128;
    int srow = t >> 2, scol8 = (t & 3) * 8;

    f32x4 acc[4][4] = {};
    for (int k0 = 0; k0 < 128; k0 += 32) {
        gload_lds16(A + (size_t)(m0 + srow) * 128 + k0 + scol8,      As + t * 8);
        gload_lds16(A + (size_t)(m0 + 64 + srow) * 128 + k0 + scol8, As + 2048 + t * 8);
        gload_lds16(Bt + (size_t)(n0 + srow) * 128 + k0 + scol8,      Bs + t * 8);
        gload_lds16(Bt + (size_t)(n0 + 64 + srow) * 128 + k0 + scol8, Bs + 2048 + t * 8);
        __syncthreads();
        bf16x8 af[4], bfr[4];
#pragma unroll
        for (int mi = 0; mi < 4; ++mi)
            af[mi] = *(const bf16x8*)(&As[(wr * 64 + mi * 16 + lrow) * 32 + kq * 8]);
#pragma unroll
        for (int ni = 0; ni < 4; ++ni)
            bfr[ni] = *(const bf16x8*)(&Bs[(wc * 64 + ni * 16 + lrow) * 32 + kq * 8]);
#pragma unroll
        for (int mi = 0; mi < 4; ++mi)
#pragma unroll
            for (int ni = 0; ni < 4; ++ni)
                acc[mi][ni] = __builtin_amdgcn_mfma_f32_16x16x32_bf16(af[mi], bfr[ni], acc[mi][ni], 0, 0, 0);
        __syncthreads();
    }

    float scale = (region == 0) ? QSCALE : 1.f;
#pragma unroll
    for (int ni = 0; ni < 4; ++ni) {
        int col = wc * 64 + ni * 16 + lrow;
#pragma unroll
        for (int mi = 0; mi < 4; ++mi) {
#pragma unroll
            for (int r = 0; r < 4; ++r) {
                int row = wr * 64 + mi * 16 + kq * 4 + r;
                smem[row * QST + col] = f2h(acc[mi][ni][r] * scale);
            }
        }
    }
    __syncthreads();
    if (region == 0) {
        unsigned short* outp = qb + (size_t)m0 * 128;
#pragma unroll
        for (int i = 0; i < 8; ++i) {
            int chunk = i * 256 + t;
            int row = chunk >> 4, c16 = chunk & 15;
            *(float4*)(outp + (size_t)chunk * 8) = *(const float4*)(smem + row * QST + c16 * 8);
        }
    } else {
        // fp8 convert + coalesced 16B stores; uint LDS reads (not scalar ushort)
        int half = region - 1;   // 0:k, 1:v
#pragma unroll
        for (int i = 0; i < 4; ++i) {
            int chunk = i * 256 + t;         // 0..1023
            int row = chunk >> 3, seg = chunk & 7;
            const unsigned int* sp = (const unsigned int*)(smem + row * QST + seg * 16);
            unsigned int ow[4];
#pragma unroll
            for (int j = 0; j < 4; ++j) {
                unsigned int u0 = sp[2 * j], u1 = sp[2 * j + 1];
                unsigned int lo = pk_fp8(h2f((unsigned short)(u0 & 0xffff)),
                                         h2f((unsigned short)(u0 >> 16)));
                unsigned int hi = pk_fp8(h2f((unsigned short)(u1 & 0xffff)),
                                         h2f((unsigned short)(u1 >> 16)));
                ow[j] = lo | (hi << 16);
            }
            *(uint4*)(kv8 + (size_t)(m0 + row) * 256 + half * 128 + seg * 16) =
                make_uint4(ow[0], ow[1], ow[2], ow[3]);
        }
    }
}

// ---------------- k6: fused attention aggregate + residual + LN1 ----------------
// Head-per-lane scoring: lane = (edge slot l>>3, head l&7); full 16-dim dot per lane,
// NO shuffles for score reduction; one bpermute per edge to fetch weights for v-agg.
__global__ __launch_bounds__(256) void agg_ln1_kernel(
        const unsigned short* __restrict__ qb, const unsigned char* __restrict__ kv8,
        const float* __restrict__ feat,
        const int* __restrict__ srcs, const int* __restrict__ offsets,
        const float* __restrict__ g, const float* __restrict__ b,
        unsigned short* __restrict__ rstb, int n) {
    int node = blockIdx.x * 4 + (threadIdx.x >> 6);
    int lane = threadIdx.x & 63;
    if (node >= n) return;
    int eo = lane >> 3;    // edge slot in 8-chunk
    int h  = lane & 7;     // head

    // load q for head h: 16 f16 (pre-scaled) -> 16 floats
    float qf[16];
    {
        uint4 qa = *(const uint4*)(qb + (size_t)node * 128 + h * 16);
        uint4 qc = *(const uint4*)(qb + (size_t)node * 128 + h * 16 + 8);
        unsigned int uu[8] = {qa.x, qa.y, qa.z, qa.w, qc.x, qc.y, qc.z, qc.w};
#pragma unroll
        for (int j = 0; j < 8; ++j) {
            f16x2 p = __builtin_bit_cast(f16x2, uu[j]);
            qf[2 * j] = (float)p.x; qf[2 * j + 1] = (float)p.y;
        }
    }

    int beg = offsets[node], end = offsets[node + 1];
    float l = 0.f, a0 = 0.f, a1 = 0.f;
    const unsigned short* vtab = (const unsigned short*)kv8;  // v word idx: s*128 + 64 + lane

    for (int idx = beg; idx < end; idx += 8) {
        int ie = idx + eo;
        bool val = ie < end;
        int smy = val ? srcs[ie] : 0;
        uint4 kw = *(const uint4*)(kv8 + (size_t)smy * 256 + h * 16);
        float p = 0.f;
        {
            f32x2 kk;
            kk = unpk_fp8<false>(kw.x); p = fmaf(kk.x, qf[0],  p); p = fmaf(kk.y, qf[1],  p);
            kk = unpk_fp8<true >(kw.x); p = fmaf(kk.x, qf[2],  p); p = fmaf(kk.y, qf[3],  p);
            kk = unpk_fp8<false>(kw.y); p = fmaf(kk.x, qf[4],  p); p = fmaf(kk.y, qf[5],  p);
            kk = unpk_fp8<true >(kw.y); p = fmaf(kk.x, qf[6],  p); p = fmaf(kk.y, qf[7],  p);
            kk = unpk_fp8<false>(kw.z); p = fmaf(kk.x, qf[8],  p); p = fmaf(kk.y, qf[9],  p);
            kk = unpk_fp8<true >(kw.z); p = fmaf(kk.x, qf[10], p); p = fmaf(kk.y, qf[11], p);
            kk = unpk_fp8<false>(kw.w); p = fmaf(kk.x, qf[12], p); p = fmaf(kk.y, qf[13], p);
            kk = unpk_fp8<true >(kw.w); p = fmaf(kk.x, qf[14], p); p = fmaf(kk.y, qf[15], p);
        }
        p = fminf(fmaxf(p, -30.f), 30.f);
        float w = val ? fexp2(p) : 0.f;
        // v-aggregation: lane owns dims (2*lane, 2*lane+1); its head is lane>>3
#pragma unroll
        for (int e = 0; e < 8; ++e) {
            int ie2 = idx + e;
            int se = (ie2 < end) ? srcs[ie2] : 0;   // broadcast load; we=0 masks invalid
            float we = __shfl(w, e * 8 + (lane >> 3), 64);
            unsigned int vv = vtab[(size_t)se * 128 + 64 + lane];
            f32x2 vf = unpk_fp8<false>(vv);
            l += we;
            a0 = fmaf(vf.x, we, a0);
            a1 = fmaf(vf.y, we, a1);
        }
    }

    float inv = (l > 0.f) ? 1.f / l : 0.f;
    float2 fv = *(const float2*)(feat + (size_t)node * DIM + 2 * lane);
    float x0 = a0 * inv + fv.x;
    float x1 = a1 * inv + fv.y;

    float s1 = x0 + x1;
    float s2 = x0 * x0 + x1 * x1;
#pragma unroll
    for (int off = 1; off < 64; off <<= 1) {
        s1 += __shfl_xor(s1, off, 64);
        s2 += __shfl_xor(s2, off, 64);
    }
    float mean = s1 * (1.f / DIM);
    float var = s2 * (1.f / DIM) - mean * mean;
    float rinv = rsqrtf(var + LN_EPS);
    float g0 = g[2 * lane], g1 = g[2 * lane + 1];
    float b0 = b[2 * lane], b1 = b[2 * lane + 1];
    float o0 = (x0 - mean) * rinv * g0 + b0;
    float o1 = (x1 - mean) * rinv * g1 + b1;
    unsigned int packed = (unsigned int)f2bf(o0) | ((unsigned int)f2bf(o1) << 16);
    ((unsigned int*)rstb)[(size_t)node * 64 + lane] = packed;
}

// ---------------- k7: FFN1: hid = PReLU(rst @ W1 + b1), bf16 out ----------------
__global__ __launch_bounds__(256) void ffn1_gemm(
        const unsigned short* __restrict__ A, const unsigned short* __restrict__ Bt,
        unsigned short* __restrict__ hid,
        const float* __restrict__ b1, const float* __restrict__ prelu) {
    __shared__ unsigned short smem[128 * QST];
    unsigned short* As = smem;
    unsigned short* Bs = smem + 4096;
    int t = threadIdx.x;
    int wave = t >> 6, lane = t & 63;
    int wr = wave >> 1, wc = wave & 1;
    int lrow = lane & 15, kq = lane >> 4;
    int m0 = blockIdx.y * 128;
    int n0 = blockIdx.x * 128;
    int srow = t >> 2, scol8 = (t & 3) * 8;

    f32x4 acc[4][4] = {};
    for (int k0 = 0; k0 < 128; k0 += 32) {
        gload_lds16(A + (size_t)(m0 + srow) * 128 + k0 + scol8,      As + t * 8);
        gload_lds16(A + (size_t)(m0 + 64 + srow) * 128 + k0 + scol8, As + 2048 + t * 8);
        gload_lds16(Bt + (size_t)(n0 + srow) * 128 + k0 + scol8,      Bs + t * 8);
        gload_lds16(Bt + (size_t)(n0 + 64 + srow) * 128 + k0 + scol8, Bs + 2048 + t * 8);
        __syncthreads();
        bf16x8 af[4], bfr[4];
#pragma unroll
        for (int mi = 0; mi < 4; ++mi)
            af[mi] = *(const bf16x8*)(&As[(wr * 64 + mi * 16 + lrow) * 32 + kq * 8]);
#pragma unroll
        for (int ni = 0; ni < 4; ++ni)
            bfr[ni] = *(const bf16x8*)(&Bs[(wc * 64 + ni * 16 + lrow) * 32 + kq * 8]);
#pragma unroll
        for (int mi = 0; mi < 4; ++mi)
#pragma unroll
            for (int ni = 0; ni < 4; ++ni)
                acc[mi][ni] = __builtin_amdgcn_mfma_f32_16x16x32_bf16(af[mi], bfr[ni], acc[mi][ni], 0, 0, 0);
        __syncthreads();
    }

#pragma unroll
    for (int ni = 0; ni < 4; ++ni) {
        int col = wc * 64 + ni * 16 + lrow;
        int cg = n0 + col;
        float biv = b1[cg], pwv = prelu[cg];
#pragma unroll
        for (int mi = 0; mi < 4; ++mi) {
#pragma unroll
            for (int r = 0; r < 4; ++r) {
                int row = wr * 64 + mi * 16 + kq * 4 + r;
                float v = acc[mi][ni][r] + biv;
                v = v >= 0.f ? v : pwv * v;
                smem[row * QST + col] = f2bf(v);
            }
        }
    }
    __syncthreads();
#pragma unroll
    for (int i = 0; i < 8; ++i) {
        int chunk = i * 256 + t;
        int row = chunk >> 4, c16 = chunk & 15;
        *(float4*)(hid + (size_t)(m0 + row) * 512 + n0 + c16 * 8) =
            *(const float4*)(smem + row * QST + c16 * 8);
    }
}

// ---------------- k8: FFN2 + residual + LN2 ----------------
__global__ __launch_bounds__(256) void ffn2_ln2_kernel(
        const unsigned short* __restrict__ hid, const unsigned short* __restrict__ W2t,
        const unsigned short* __restrict__ rstb,
        const float* __restrict__ b2, const float* __restrict__ g, const float* __restrict__ bb,
        float* __restrict__ out, int Nn) {
    __shared__ unsigned short As[64 * 32];
    __shared__ unsigned short Bs[128 * 32];
    __shared__ float redS[64][4];
    __shared__ float redQ[64][4];
    int t = threadIdx.x;
    int wave = t >> 6, lane = t & 63;
    int lrow = lane & 15, kq = lane >> 4;
    int m0 = blockIdx.x * 64;
    int srow = t >> 2, scol8 = (t & 3) * 8;

    f32x4 acc[4][2] = {};
    for (int k0 = 0; k0 < 512; k0 += 32) {
        gload_lds16(hid + (size_t)(m0 + srow) * 512 + k0 + scol8, As + t * 8);
        gload_lds16(W2t + (size_t)srow * 512 + k0 + scol8,        Bs + t * 8);
        gload_lds16(W2t + (size_t)(64 + srow) * 512 + k0 + scol8, Bs + 2048 + t * 8);
        __syncthreads();
        bf16x8 af[4], bfr[2];
#pragma unroll
        for (int mi = 0; mi < 4; ++mi)
            af[mi] = *(const bf16x8*)(&As[(mi * 16 + lrow) * 32 + kq * 8]);
#pragma unroll
        for (int ni = 0; ni < 2; ++ni)
            bfr[ni] = *(const bf16x8*)(&Bs[(wave * 32 + ni * 16 + lrow) * 32 + kq * 8]);
#pragma unroll
        for (int mi = 0; mi < 4; ++mi)
#pragma unroll
            for (int ni = 0; ni < 2; ++ni)
                acc[mi][ni] = __builtin_amdgcn_mfma_f32_16x16x32_bf16(af[mi], bfr[ni], acc[mi][ni], 0, 0, 0);
        __syncthreads();
    }

    float b2v[2], gv[2], bv[2];
    int cols[2];
#pragma unroll
    for (int ni = 0; ni < 2; ++ni) {
        cols[ni] = wave * 32 + ni * 16 + lrow;
        b2v[ni] = b2[cols[ni]]; gv[ni] = g[cols[ni]]; bv[ni] = bb[cols[ni]];
    }
#pragma unroll
    for (int mi = 0; mi < 4; ++mi) {
#pragma unroll
        for (int r = 0; r < 4; ++r) {
            int rloc = mi * 16 + kq * 4 + r;
            int row = m0 + rloc;
            float ps = 0.f, pq = 0.f;
#pragma unroll
            for (int ni = 0; ni < 2; ++ni) {
                float rsv = bf2f(rstb[(size_t)row * 128 + cols[ni]]);
                float v = acc[mi][ni][r] + b2v[ni] + rsv;
                acc[mi][ni][r] = v;
                ps += v; pq += v * v;
            }
#pragma unroll
            for (int off = 1; off < 16; off <<= 1) {
                ps += __shfl_xor(ps, off, 16);
                pq += __shfl_xor(pq, off, 16);
            }
            if (lrow == 0) { redS[rloc][wave] = ps; redQ[rloc][wave] = pq; }
        }
    }
    __syncthreads();
#pragma unroll
    for (int mi = 0; mi < 4; ++mi) {
#pragma unroll
        for (int r = 0; r < 4; ++r) {
            int rloc = mi * 16 + kq * 4 + r;
            int row = m0 + rloc;
            float s1 = redS[rloc][0] + redS[rloc][1] + redS[rloc][2] + redS[rloc][3];
            float sq = redQ[rloc][0] + redQ[rloc][1] + redQ[rloc][2] + redQ[rloc][3];
            float mean = s1 * (1.f / DIM);
            float var = sq * (1.f / DIM) - mean * mean;
            float rs = rsqrtf(var + LN_EPS);
            if (row < Nn) {
#pragma unroll
                for (int ni = 0; ni < 2; ++ni)
                    out[(size_t)row * 128 + cols[ni]] =
                        (acc[mi][ni][r] - mean) * rs * gv[ni] + bv[ni];
            }
        }
    }
}

// ---------------- launch ----------------

extern "C" void kernel_launch(void* const* d_in, const int* in_sizes, int n_in,
                              void* d_out, int out_size, void* d_ws, size_t ws_size,
                              hipStream_t stream) {
    const float* feat   = (const float*)d_in[0];
    const int*   src    = (const int*)d_in[1];
    const int*   dst    = (const int*)d_in[2];
    const float* Wq     = (const float*)d_in[3];
    const float* Wk     = (const float*)d_in[4];
    const float* Wv     = (const float*)d_in[5];
    const float* ln1_g  = (const float*)d_in[6];
    const float* ln1_b  = (const float*)d_in[7];
    const float* ln2_g  = (const float*)d_in[8];
    const float* ln2_b  = (const float*)d_in[9];
    const float* W1     = (const float*)d_in[10];
    const float* b1     = (const float*)d_in[11];
    const float* prelu  = (const float*)d_in[12];
    const float* W2     = (const float*)d_in[13];
    const float* b2     = (const float*)d_in[14];
    float* out = (float*)d_out;

    const int Nn = in_sizes[0] / DIM;        // 40000
    const int E  = in_sizes[1];              // 640000
    const int MP = (Nn + 127) & ~127;        // 40064

    char* w = (char*)d_ws;
    unsigned short* qb   = (unsigned short*)w; w += (size_t)MP * DIM * 2;
    unsigned char*  kv8  = (unsigned char*)w;  w += (size_t)MP * 256;   // 128B k | 128B v
    unsigned short* rstb = (unsigned short*)w; w += (size_t)MP * DIM * 2;
    unsigned short* featb= (unsigned short*)w; w += (size_t)MP * DIM * 2;
    unsigned short* hid  = (unsigned short*)w; w += (size_t)MP * HID * 2;
    unsigned short* Wqkvt= (unsigned short*)w; w += 3 * DIM * DIM * 2;
    unsigned short* W1t  = (unsigned short*)w; w += (size_t)HID * DIM * 2;
    unsigned short* W2t  = (unsigned short*)w; w += (size_t)DIM * HID * 2;
    int* counts  = (int*)w;  w += (size_t)Nn * 4;
    int* offsets = (int*)w;  w += (size_t)(Nn + 4) * 4;
    int* bsum    = (int*)w;  w += 64 * 4;
    int* srcs    = (int*)w;

    const int NCH = (Nn + 1023) / 1024;      // 40 (<= 64)
    const int FB  = Nn / 8;                  // featb blocks
    const int WB  = FB + 704;                // + weight transpose blocks
    const int CB  = (E + 1023) / 1024;       // count blocks

    hipMemsetAsync(counts, 0, (size_t)Nn * 4, stream);

    prep_count_kernel<<<WB + CB, 256, 0, stream>>>(
        counts, Nn, feat, featb, Wq, Wk, Wv, Wqkvt, W1, W1t, W2, W2t, dst, E, FB, WB);

    scanA_kernel<<<NCH, 256, 0, stream>>>(counts, bsum, Nn);
    scanC_kernel<<<NCH, 256, 0, stream>>>(counts, bsum, offsets, Nn, NCH);

    fill_kernel<<<CB, 256, 0, stream>>>(dst, src, counts, srcs, E);

    {
        dim3 grid(3, MP / 128);
        qkv_gemm<<<grid, 256, 0, stream>>>(featb, Wqkvt, qb, kv8);
    }

    agg_ln1_kernel<<<(Nn + 3) / 4, 256, 0, stream>>>(qb, kv8, feat, srcs, offsets,
                                                     ln1_g, ln1_b, rstb, Nn);

    {
        dim3 grid(4, MP / 128);
        ffn1_gemm<<<grid, 256, 0, stream>>>(rstb, W1t, hid, b1, prelu);
    }

    ffn2_ln2_kernel<<<MP / 64, 256, 0, stream>>>(hid, W2t, rstb, b2, ln2_g, ln2_b, out, Nn);
}

// Round 12
// 273.017 us; speedup vs baseline: 1.0228x; 1.0228x over previous
//
#include <hip/hip_runtime.h>
#include <hip/hip_bf16.h>
#include <math.h>

#define DIM 128
#define NHEAD 8
#define DHEAD 16
#define HID 512
#define LN_EPS 1e-5f
// (1/sqrt(128))*log2(e) folded into q so softmax runs in exp2 domain
#define QSCALE 0.12751879104863297f

typedef __bf16 bf16x8 __attribute__((ext_vector_type(8)));
typedef float f32x4 __attribute__((ext_vector_type(4)));
typedef float f32x2 __attribute__((ext_vector_type(2)));
typedef _Float16 f16x2 __attribute__((ext_vector_type(2)));

__device__ inline float bf2f(unsigned int bits16) {
    return __uint_as_float(bits16 << 16);
}
__device__ inline unsigned short f2bf(float f) {
    unsigned int u = __float_as_uint(f);
    unsigned int r = u + 0x7fff + ((u >> 16) & 1);   // RNE
    return (unsigned short)(r >> 16);
}
__device__ inline unsigned short f2h(float f) {
    _Float16 h = (_Float16)f;
    return __builtin_bit_cast(unsigned short, h);
}
__device__ inline float h2f(unsigned short h) {
    return (float)__builtin_bit_cast(_Float16, h);
}
// pack two floats -> two OCP e4m3 bytes (low ushort)
__device__ inline unsigned short pk_fp8(float a, float b) {
    int r = __builtin_amdgcn_cvt_pk_fp8_f32(a, b, 0, false);
    return (unsigned short)(r & 0xffff);
}
// unpack 2 fp8 bytes; HI=false: bytes 0,1; HI=true: bytes 2,3
template <bool HI>
__device__ inline f32x2 unpk_fp8(unsigned int w) {
    return __builtin_amdgcn_cvt_pk_f32_fp8((int)w, HI);
}
__device__ inline float fexp2(float x) { return __builtin_amdgcn_exp2f(x); }

// async global->LDS, 16B per lane
__device__ inline void gload_lds16(const void* g, void* l) {
    __builtin_amdgcn_global_load_lds(
        (const __attribute__((address_space(1))) unsigned int*)g,
        (__attribute__((address_space(3))) unsigned int*)l, 16, 0, 0);
}

// ---------------- k1: prep (feat->bf16, weight transposes) + count atomics ----------------
__global__ __launch_bounds__(256) void prep_count_kernel(
        int* counts, int Nn,
        const float* __restrict__ feat, unsigned short* __restrict__ featb,
        const float* __restrict__ Wq, const float* __restrict__ Wk, const float* __restrict__ Wv,
        unsigned short* __restrict__ Wqkvt,
        const float* __restrict__ W1, unsigned short* __restrict__ W1t,
        const float* __restrict__ W2, unsigned short* __restrict__ W2t,
        const int* __restrict__ dst, int E, int fb, int wb) {
    int blk = blockIdx.x, t = threadIdx.x;
    if (blk < fb) {
        int i = blk * 256 + t;            // quad index
        if (i < Nn * 32) {
            float4 v = *(const float4*)(feat + (size_t)i * 4);
            ushort4 o;
            o.x = f2bf(v.x); o.y = f2bf(v.y); o.z = f2bf(v.z); o.w = f2bf(v.w);
            *(ushort4*)(featb + (size_t)i * 4) = o;
        }
    } else if (blk < wb) {
        int b2_ = blk - fb;
        if (b2_ < 192) {
            int sec = b2_ >> 6;
            const float* W = sec == 0 ? Wq : (sec == 1 ? Wk : Wv);
            int o = (b2_ & 63) * 256 + t;
            int oc = o >> 7, orow = o & 127;
            Wqkvt[sec * 16384 + o] = f2bf(W[(size_t)orow * 128 + oc]);
        } else if (b2_ < 448) {
            int o = (b2_ - 192) * 256 + t;
            int oc = o >> 7, orow = o & 127;
            W1t[o] = f2bf(W1[(size_t)orow * 512 + oc]);
        } else {
            int o = (b2_ - 448) * 256 + t;
            int oc = o >> 9, orow = o & 511;
            W2t[o] = f2bf(W2[(size_t)orow * 128 + oc]);
        }
    } else {
        int e0 = (blk - wb) * 1024 + t * 4;
        if (e0 + 3 < E) {
            int4 d = *(const int4*)(dst + e0);
            atomicAdd(&counts[d.x], 1);
            atomicAdd(&counts[d.y], 1);
            atomicAdd(&counts[d.z], 1);
            atomicAdd(&counts[d.w], 1);
        } else {
            for (int e = e0; e < E; ++e) atomicAdd(&counts[dst[e]], 1);
        }
    }
}

// ---------------- scan ----------------

__global__ __launch_bounds__(256) void scanA_kernel(const int* __restrict__ counts, int* bsum, int Nn) {
    int blk = blockIdx.x, t = threadIdx.x;
    int i = blk * 1024 + t * 4;
    int s = 0;
    if (i < Nn) { int4 x = *(const int4*)(counts + i); s = x.x + x.y + x.z + x.w; }
#pragma unroll
    for (int off = 1; off < 64; off <<= 1) s += __shfl_xor(s, off, 64);
    __shared__ int wt[4];
    if ((t & 63) == 0) wt[t >> 6] = s;
    __syncthreads();
    if (t == 0) bsum[blk] = wt[0] + wt[1] + wt[2] + wt[3];
}

__global__ __launch_bounds__(256) void scanC_kernel(int* counts, const int* __restrict__ bsum,
                                                    int* offsets, int Nn, int NCH) {
    int blk = blockIdx.x, t = threadIdx.x, lane = t & 63, wv = t >> 6;
    __shared__ int wt[4];
    __shared__ int base_s;
    if (wv == 0) {
        int v = (lane < NCH) ? bsum[lane] : 0;
        int s = v;
#pragma unroll
        for (int off = 1; off < 64; off <<= 1) {
            int u = __shfl_up(s, off, 64);
            if (lane >= off) s += u;
        }
        int basev = (blk > 0) ? __shfl(s, blk - 1, 64) : 0;
        int tot = __shfl(s, NCH - 1, 64);
        if (lane == 0) {
            base_s = basev;
            if (blk == 0) offsets[Nn] = tot;
        }
    }
    int i = blk * 1024 + t * 4;
    int4 x = make_int4(0, 0, 0, 0);
    if (i < Nn) x = *(const int4*)(counts + i);
    int ts = x.x + x.y + x.z + x.w;
    int s = ts;
#pragma unroll
    for (int off = 1; off < 64; off <<= 1) {
        int u = __shfl_up(s, off, 64);
        if (lane >= off) s += u;
    }
    if (lane == 63) wt[wv] = s;
    __syncthreads();
    int woff = 0;
    for (int wi = 0; wi < wv; ++wi) woff += wt[wi];
    int excl = base_s + woff + (s - ts);
    if (i < Nn) {
        int o0 = excl, o1 = o0 + x.x, o2 = o1 + x.y, o3 = o2 + x.z;
        *(int4*)(offsets + i) = make_int4(o0, o1, o2, o3);
        *(int4*)(counts + i) = make_int4(o0, o1, o2, o3);
    }
}

// ---------------- k4: fill (CSR scatter) — no LDS, high occupancy ----------------
__global__ void fill_kernel(const int* __restrict__ dst, const int* __restrict__ src,
                            int* cursor, int* srcs, int E) {
    int e0 = (blockIdx.x * blockDim.x + threadIdx.x) * 4;
    if (e0 + 3 < E) {
        int4 d = *(const int4*)(dst + e0);
        int4 sv = *(const int4*)(src + e0);
        srcs[atomicAdd(&cursor[d.x], 1)] = sv.x;
        srcs[atomicAdd(&cursor[d.y], 1)] = sv.y;
        srcs[atomicAdd(&cursor[d.z], 1)] = sv.z;
        srcs[atomicAdd(&cursor[d.w], 1)] = sv.w;
    } else {
        for (int e = e0; e < E; ++e) srcs[atomicAdd(&cursor[dst[e]], 1)] = src[e];
    }
}

// ---------------- k5: qkv GEMM -> f16 q (pre-scaled), fp8 kv8 table ----------------
// grid (3, MP/128): region 0:q 1:k 2:v. kv8 per node: 128B k-fp8 | 128B v-fp8 (dim order).
#define QST 136
__global__ __launch_bounds__(256) void qkv_gemm(
        const unsigned short* __restrict__ A, const unsigned short* __restrict__ Bt,
        unsigned short* __restrict__ qb, unsigned char* __restrict__ kv8) {
    __shared__ unsigned short smem[128 * QST];
    unsigned short* As = smem;
    unsigned short* Bs = smem + 4096;
    int t = threadIdx.x;
    int wave = t >> 6, lane = t & 63;
    int wr = wave >> 1, wc = wave & 1;
    int lrow = lane & 15, kq = lane >> 4;
    int m0 = blockIdx.y * 128;
    int region = blockIdx.x;
    int n0 = region * 128;
    int srow = t >> 2, scol8 = (t & 3) * 8;

    f32x4 acc[4][4] = {};
    for (int k0 = 0; k0 < 128; k0 += 32) {
        gload_lds16(A + (size_t)(m0 + srow) * 128 + k0 + scol8,      As + t * 8);
        gload_lds16(A + (size_t)(m0 + 64 + srow) * 128 + k0 + scol8, As + 2048 + t * 8);
        gload_lds16(Bt + (size_t)(n0 + srow) * 128 + k0 + scol8,      Bs + t * 8);
        gload_lds16(Bt + (size_t)(n0 + 64 + srow) * 128 + k0 + scol8, Bs + 2048 + t * 8);
        __syncthreads();
        bf16x8 af[4], bfr[4];
#pragma unroll
        for (int mi = 0; mi < 4; ++mi)
            af[mi] = *(const bf16x8*)(&As[(wr * 64 + mi * 16 + lrow) * 32 + kq * 8]);
#pragma unroll
        for (int ni = 0; ni < 4; ++ni)
            bfr[ni] = *(const bf16x8*)(&Bs[(wc * 64 + ni * 16 + lrow) * 32 + kq * 8]);
#pragma unroll
        for (int mi = 0; mi < 4; ++mi)
#pragma unroll
            for (int ni = 0; ni < 4; ++ni)
                acc[mi][ni] = __builtin_amdgcn_mfma_f32_16x16x32_bf16(af[mi], bfr[ni], acc[mi][ni], 0, 0, 0);
        __syncthreads();
    }

    float scale = (region == 0) ? QSCALE : 1.f;
#pragma unroll
    for (int ni = 0; ni < 4; ++ni) {
        int col = wc * 64 + ni * 16 + lrow;
#pragma unroll
        for (int mi = 0; mi < 4; ++mi) {
#pragma unroll
            for (int r = 0; r < 4; ++r) {
                int row = wr * 64 + mi * 16 + kq * 4 + r;
                smem[row * QST + col] = f2h(acc[mi][ni][r] * scale);
            }
        }
    }
    __syncthreads();
    if (region == 0) {
        unsigned short* outp = qb + (size_t)m0 * 128;
#pragma unroll
        for (int i = 0; i < 8; ++i) {
            int chunk = i * 256 + t;
            int row = chunk >> 4, c16 = chunk & 15;
            *(float4*)(outp + (size_t)chunk * 8) = *(const float4*)(smem + row * QST + c16 * 8);
        }
    } else {
        // fp8 convert + coalesced 16B stores; uint LDS reads
        int half = region - 1;   // 0:k, 1:v
#pragma unroll
        for (int i = 0; i < 4; ++i) {
            int chunk = i * 256 + t;         // 0..1023
            int row = chunk >> 3, seg = chunk & 7;
            const unsigned int* sp = (const unsigned int*)(smem + row * QST + seg * 16);
            unsigned int ow[4];
#pragma unroll
            for (int j = 0; j < 4; ++j) {
                unsigned int u0 = sp[2 * j], u1 = sp[2 * j + 1];
                unsigned int lo = pk_fp8(h2f((unsigned short)(u0 & 0xffff)),
                                         h2f((unsigned short)(u0 >> 16)));
                unsigned int hi = pk_fp8(h2f((unsigned short)(u1 & 0xffff)),
                                         h2f((unsigned short)(u1 >> 16)));
                ow[j] = lo | (hi << 16);
            }
            *(uint4*)(kv8 + (size_t)(m0 + row) * 256 + half * 128 + seg * 16) =
                make_uint4(ow[0], ow[1], ow[2], ow[3]);
        }
    }
}

// ---------------- k6: fused attention aggregate + residual + LN1 ----------------
// Dim-per-lane (2 fp8 k + 2 fp8 v dims per lane), 16-edge masked chunks ->
// 32 independent dword gathers in flight per wave. exp2-domain softmax, no max.
__global__ __launch_bounds__(256) void agg_ln1_kernel(
        const unsigned short* __restrict__ qb, const unsigned short* __restrict__ kvu,
        const float* __restrict__ feat,
        const int* __restrict__ srcs, const int* __restrict__ offsets,
        const float* __restrict__ g, const float* __restrict__ b,
        unsigned short* __restrict__ rstb, int n) {
    int node = blockIdx.x * 4 + (threadIdx.x >> 6);
    int lane = threadIdx.x & 63;
    if (node >= n) return;

    unsigned int qw = ((const unsigned int*)qb)[(size_t)node * 64 + lane];
    f16x2 qp = __builtin_bit_cast(f16x2, qw);
    float q0 = (float)qp.x, q1 = (float)qp.y;

    int beg = offsets[node], end = offsets[node + 1];
    float l = 0.f, a0 = 0.f, a1 = 0.f;

    for (int idx = beg; idx < end; idx += 16) {
        int sa[16];
#pragma unroll
        for (int i = 0; i < 16; ++i) {
            int ii = idx + i;
            sa[i] = (ii < end) ? srcs[ii] : -1;
        }
        unsigned int kw[16], vw[16];
#pragma unroll
        for (int i = 0; i < 16; ++i) {
            int s = sa[i] < 0 ? 0 : sa[i];
            kw[i] = kvu[(size_t)s * 128 + lane];
        }
#pragma unroll
        for (int i = 0; i < 16; ++i) {
            int s = sa[i] < 0 ? 0 : sa[i];
            vw[i] = kvu[(size_t)s * 128 + 64 + lane];
        }
        float sc[16];
#pragma unroll
        for (int i = 0; i < 16; ++i) {
            f32x2 kk = unpk_fp8<false>(kw[i]);
            float p = fmaf(kk.x, q0, kk.y * q1);
            p += __shfl_xor(p, 1, 8);
            p += __shfl_xor(p, 2, 8);
            p += __shfl_xor(p, 4, 8);
            p = fminf(fmaxf(p, -30.f), 30.f);
            sc[i] = (sa[i] < 0) ? -1000.f : p;
        }
#pragma unroll
        for (int i = 0; i < 16; ++i) {
            float ww = fexp2(sc[i]);
            f32x2 vv = unpk_fp8<false>(vw[i]);
            l += ww;
            a0 = fmaf(vv.x, ww, a0);
            a1 = fmaf(vv.y, ww, a1);
        }
    }

    float inv = (l > 0.f) ? 1.f / l : 0.f;
    float2 fv = *(const float2*)(feat + (size_t)node * DIM + 2 * lane);
    float x0 = a0 * inv + fv.x;
    float x1 = a1 * inv + fv.y;

    float s1 = x0 + x1;
    float s2 = x0 * x0 + x1 * x1;
#pragma unroll
    for (int off = 1; off < 64; off <<= 1) {
        s1 += __shfl_xor(s1, off, 64);
        s2 += __shfl_xor(s2, off, 64);
    }
    float mean = s1 * (1.f / DIM);
    float var = s2 * (1.f / DIM) - mean * mean;
    float rinv = rsqrtf(var + LN_EPS);
    float g0 = g[2 * lane], g1 = g[2 * lane + 1];
    float b0 = b[2 * lane], b1 = b[2 * lane + 1];
    float o0 = (x0 - mean) * rinv * g0 + b0;
    float o1 = (x1 - mean) * rinv * g1 + b1;
    unsigned int packed = (unsigned int)f2bf(o0) | ((unsigned int)f2bf(o1) << 16);
    ((unsigned int*)rstb)[(size_t)node * 64 + lane] = packed;
}

// ---------------- k7: FFN1: hid = PReLU(rst @ W1 + b1), bf16 out ----------------
__global__ __launch_bounds__(256) void ffn1_gemm(
        const unsigned short* __restrict__ A, const unsigned short* __restrict__ Bt,
        unsigned short* __restrict__ hid,
        const float* __restrict__ b1, const float* __restrict__ prelu) {
    __shared__ unsigned short smem[128 * QST];
    unsigned short* As = smem;
    unsigned short* Bs = smem + 4096;
    int t = threadIdx.x;
    int wave = t >> 6, lane = t & 63;
    int wr = wave >> 1, wc = wave & 1;
    int lrow = lane & 15, kq = lane >> 4;
    int m0 = blockIdx.y * 128;
    int n0 = blockIdx.x * 128;
    int srow = t >> 2, scol8 = (t & 3) * 8;

    f32x4 acc[4][4] = {};
    for (int k0 = 0; k0 < 128; k0 += 32) {
        gload_lds16(A + (size_t)(m0 + srow) * 128 + k0 + scol8,      As + t * 8);
        gload_lds16(A + (size_t)(m0 + 64 + srow) * 128 + k0 + scol8, As + 2048 + t * 8);
        gload_lds16(Bt + (size_t)(n0 + srow) * 128 + k0 + scol8,      Bs + t * 8);
        gload_lds16(Bt + (size_t)(n0 + 64 + srow) * 128 + k0 + scol8, Bs + 2048 + t * 8);
        __syncthreads();
        bf16x8 af[4], bfr[4];
#pragma unroll
        for (int mi = 0; mi < 4; ++mi)
            af[mi] = *(const bf16x8*)(&As[(wr * 64 + mi * 16 + lrow) * 32 + kq * 8]);
#pragma unroll
        for (int ni = 0; ni < 4; ++ni)
            bfr[ni] = *(const bf16x8*)(&Bs[(wc * 64 + ni * 16 + lrow) * 32 + kq * 8]);
#pragma unroll
        for (int mi = 0; mi < 4; ++mi)
#pragma unroll
            for (int ni = 0; ni < 4; ++ni)
                acc[mi][ni] = __builtin_amdgcn_mfma_f32_16x16x32_bf16(af[mi], bfr[ni], acc[mi][ni], 0, 0, 0);
        __syncthreads();
    }

#pragma unroll
    for (int ni = 0; ni < 4; ++ni) {
        int col = wc * 64 + ni * 16 + lrow;
        int cg = n0 + col;
        float biv = b1[cg], pwv = prelu[cg];
#pragma unroll
        for (int mi = 0; mi < 4; ++mi) {
#pragma unroll
            for (int r = 0; r < 4; ++r) {
                int row = wr * 64 + mi * 16 + kq * 4 + r;
                float v = acc[mi][ni][r] + biv;
                v = v >= 0.f ? v : pwv * v;
                smem[row * QST + col] = f2bf(v);
            }
        }
    }
    __syncthreads();
#pragma unroll
    for (int i = 0; i < 8; ++i) {
        int chunk = i * 256 + t;
        int row = chunk >> 4, c16 = chunk & 15;
        *(float4*)(hid + (size_t)(m0 + row) * 512 + n0 + c16 * 8) =
            *(const float4*)(smem + row * QST + c16 * 8);
    }
}

// ---------------- k8: FFN2 + residual + LN2 ----------------
__global__ __launch_bounds__(256) void ffn2_ln2_kernel(
        const unsigned short* __restrict__ hid, const unsigned short* __restrict__ W2t,
        const unsigned short* __restrict__ rstb,
        const float* __restrict__ b2, const float* __restrict__ g, const float* __restrict__ bb,
        float* __restrict__ out, int Nn) {
    __shared__ unsigned short As[64 * 32];
    __shared__ unsigned short Bs[128 * 32];
    __shared__ float redS[64][4];
    __shared__ float redQ[64][4];
    int t = threadIdx.x;
    int wave = t >> 6, lane = t & 63;
    int lrow = lane & 15, kq = lane >> 4;
    int m0 = blockIdx.x * 64;
    int srow = t >> 2, scol8 = (t & 3) * 8;

    f32x4 acc[4][2] = {};
    for (int k0 = 0; k0 < 512; k0 += 32) {
        gload_lds16(hid + (size_t)(m0 + srow) * 512 + k0 + scol8, As + t * 8);
        gload_lds16(W2t + (size_t)srow * 512 + k0 + scol8,        Bs + t * 8);
        gload_lds16(W2t + (size_t)(64 + srow) * 512 + k0 + scol8, Bs + 2048 + t * 8);
        __syncthreads();
        bf16x8 af[4], bfr[2];
#pragma unroll
        for (int mi = 0; mi < 4; ++mi)
            af[mi] = *(const bf16x8*)(&As[(mi * 16 + lrow) * 32 + kq * 8]);
#pragma unroll
        for (int ni = 0; ni < 2; ++ni)
            bfr[ni] = *(const bf16x8*)(&Bs[(wave * 32 + ni * 16 + lrow) * 32 + kq * 8]);
#pragma unroll
        for (int mi = 0; mi < 4; ++mi)
#pragma unroll
            for (int ni = 0; ni < 2; ++ni)
                acc[mi][ni] = __builtin_amdgcn_mfma_f32_16x16x32_bf16(af[mi], bfr[ni], acc[mi][ni], 0, 0, 0);
        __syncthreads();
    }

    float b2v[2], gv[2], bv[2];
    int cols[2];
#pragma unroll
    for (int ni = 0; ni < 2; ++ni) {
        cols[ni] = wave * 32 + ni * 16 + lrow;
        b2v[ni] = b2[cols[ni]]; gv[ni] = g[cols[ni]]; bv[ni] = bb[cols[ni]];
    }
#pragma unroll
    for (int mi = 0; mi < 4; ++mi) {
#pragma unroll
        for (int r = 0; r < 4; ++r) {
            int rloc = mi * 16 + kq * 4 + r;
            int row = m0 + rloc;
            float ps = 0.f, pq = 0.f;
#pragma unroll
            for (int ni = 0; ni < 2; ++ni) {
                float rsv = bf2f(rstb[(size_t)row * 128 + cols[ni]]);
                float v = acc[mi][ni][r] + b2v[ni] + rsv;
                acc[mi][ni][r] = v;
                ps += v; pq += v * v;
            }
#pragma unroll
            for (int off = 1; off < 16; off <<= 1) {
                ps += __shfl_xor(ps, off, 16);
                pq += __shfl_xor(pq, off, 16);
            }
            if (lrow == 0) { redS[rloc][wave] = ps; redQ[rloc][wave] = pq; }
        }
    }
    __syncthreads();
#pragma unroll
    for (int mi = 0; mi < 4; ++mi) {
#pragma unroll
        for (int r = 0; r < 4; ++r) {
            int rloc = mi * 16 + kq * 4 + r;
            int row = m0 + rloc;
            float s1 = redS[rloc][0] + redS[rloc][1] + redS[rloc][2] + redS[rloc][3];
            float sq = redQ[rloc][0] + redQ[rloc][1] + redQ[rloc][2] + redQ[rloc][3];
            float mean = s1 * (1.f / DIM);
            float var = sq * (1.f / DIM) - mean * mean;
            float rs = rsqrtf(var + LN_EPS);
            if (row < Nn) {
#pragma unroll
                for (int ni = 0; ni < 2; ++ni)
                    out[(size_t)row * 128 + cols[ni]] =
                        (acc[mi][ni][r] - mean) * rs * gv[ni] + bv[ni];
            }
        }
    }
}

// ---------------- launch ----------------

extern "C" void kernel_launch(void* const* d_in, const int* in_sizes, int n_in,
                              void* d_out, int out_size, void* d_ws, size_t ws_size,
                              hipStream_t stream) {
    const float* feat   = (const float*)d_in[0];
    const int*   src    = (const int*)d_in[1];
    const int*   dst    = (const int*)d_in[2];
    const float* Wq     = (const float*)d_in[3];
    const float* Wk     = (const float*)d_in[4];
    const float* Wv     = (const float*)d_in[5];
    const float* ln1_g  = (const float*)d_in[6];
    const float* ln1_b  = (const float*)d_in[7];
    const float* ln2_g  = (const float*)d_in[8];
    const float* ln2_b  = (const float*)d_in[9];
    const float* W1     = (const float*)d_in[10];
    const float* b1     = (const float*)d_in[11];
    const float* prelu  = (const float*)d_in[12];
    const float* W2     = (const float*)d_in[13];
    const float* b2     = (const float*)d_in[14];
    float* out = (float*)d_out;

    const int Nn = in_sizes[0] / DIM;        // 40000
    const int E  = in_sizes[1];              // 640000
    const int MP = (Nn + 127) & ~127;        // 40064

    char* w = (char*)d_ws;
    unsigned short* qb   = (unsigned short*)w; w += (size_t)MP * DIM * 2;
    unsigned char*  kv8  = (unsigned char*)w;  w += (size_t)MP * 256;   // 128B k | 128B v
    unsigned short* rstb = (unsigned short*)w; w += (size_t)MP * DIM * 2;
    unsigned short* featb= (unsigned short*)w; w += (size_t)MP * DIM * 2;
    unsigned short* hid  = (unsigned short*)w; w += (size_t)MP * HID * 2;
    unsigned short* Wqkvt= (unsigned short*)w; w += 3 * DIM * DIM * 2;
    unsigned short* W1t  = (unsigned short*)w; w += (size_t)HID * DIM * 2;
    unsigned short* W2t  = (unsigned short*)w; w += (size_t)DIM * HID * 2;
    int* counts  = (int*)w;  w += (size_t)Nn * 4;
    int* offsets = (int*)w;  w += (size_t)(Nn + 4) * 4;
    int* bsum    = (int*)w;  w += 64 * 4;
    int* srcs    = (int*)w;

    const int NCH = (Nn + 1023) / 1024;      // 40 (<= 64)
    const int FB  = Nn / 8;                  // featb blocks
    const int WB  = FB + 704;                // + weight transpose blocks
    const int CB  = (E + 1023) / 1024;       // count blocks

    hipMemsetAsync(counts, 0, (size_t)Nn * 4, stream);

    prep_count_kernel<<<WB + CB, 256, 0, stream>>>(
        counts, Nn, feat, featb, Wq, Wk, Wv, Wqkvt, W1, W1t, W2, W2t, dst, E, FB, WB);

    scanA_kernel<<<NCH, 256, 0, stream>>>(counts, bsum, Nn);
    scanC_kernel<<<NCH, 256, 0, stream>>>(counts, bsum, offsets, Nn, NCH);

    fill_kernel<<<CB, 256, 0, stream>>>(dst, src, counts, srcs, E);

    {
        dim3 grid(3, MP / 128);
        qkv_gemm<<<grid, 256, 0, stream>>>(featb, Wqkvt, qb, kv8);
    }

    agg_ln1_kernel<<<(Nn + 3) / 4, 256, 0, stream>>>(qb, (const unsigned short*)kv8, feat,
                                                     srcs, offsets, ln1_g, ln1_b, rstb, Nn);

    {
        dim3 grid(4, MP / 128);
        ffn1_gemm<<<grid, 256, 0, stream>>>(rstb, W1t, hid, b1, prelu);
    }

    ffn2_ln2_kernel<<<MP / 64, 256, 0, stream>>>(hid, W2t, rstb, b2, ln2_g, ln2_b, out, Nn);
}